// Round 7
// baseline (106.706 us; speedup 1.0000x reference)
//
#include <hip/hip_runtime.h>
#include <math.h>

#define WPB 4  // waves (rays) per block -> 256 threads

#define NEAR_T   2.0f
#define FAR_T    6.0f
#define EPS_W_C  1e-5f
#define EPS_T_C  1e-10f
#define FAR_DIST 1e10f

__device__ __forceinline__ float tval(int i) {
    return NEAR_T + (FAR_T - NEAR_T) * ((float)i * (1.0f / 63.0f));
}
__device__ __forceinline__ float rcp_fast(float x) {
    return __builtin_amdgcn_rcpf(x);
}

__device__ __forceinline__ float softplus_f(float x) {
    // Two-path log1p: must preserve tiny values (sigma ~1e-13 still saturates
    // alpha at dist=1e10 — R2 failure was __logf(1+e) rounding 1+e -> 1).
    const float e = __expf(-fabsf(x));
    const float big   = __logf(1.0f + e);                          // e > 2^-7
    const float small = e * (1.0f - e * (0.5f - e * 0.33333334f)); // e <= 2^-7, rel err ~1e-7
    return fmaxf(x, 0.0f) + ((e > 0.0078125f) ? big : small);
}
__device__ __forceinline__ float sigmoid_f(float x) {
    return rcp_fast(1.0f + __expf(-x));
}

// ---- DPP cross-lane (VALU pipe) ----
template<int CTRL, int MASK>
__device__ __forceinline__ float dpp_f(float x, float old) {
    return __int_as_float(__builtin_amdgcn_update_dpp(
        __float_as_int(old), __float_as_int(x), CTRL, MASK, 0xF, false));
}

__device__ __forceinline__ float scan_incl_add(float x) {
    x += dpp_f<0x111, 0xF>(x, 0.0f);
    x += dpp_f<0x112, 0xF>(x, 0.0f);
    x += dpp_f<0x114, 0xF>(x, 0.0f);
    x += dpp_f<0x118, 0xF>(x, 0.0f);
    x += dpp_f<0x142, 0xA>(x, 0.0f);   // row_bcast15
    x += dpp_f<0x143, 0xC>(x, 0.0f);   // row_bcast31
    return x;
}
__device__ __forceinline__ float scan_incl_mul(float x) {
    x *= dpp_f<0x111, 0xF>(x, 1.0f);
    x *= dpp_f<0x112, 0xF>(x, 1.0f);
    x *= dpp_f<0x114, 0xF>(x, 1.0f);
    x *= dpp_f<0x118, 0xF>(x, 1.0f);
    x *= dpp_f<0x142, 0xA>(x, 1.0f);
    x *= dpp_f<0x143, 0xC>(x, 1.0f);
    return x;
}
__device__ __forceinline__ float scan_max_f(float x) { // inclusive max-scan, values >= 0
    x = fmaxf(x, dpp_f<0x111, 0xF>(x, 0.0f));
    x = fmaxf(x, dpp_f<0x112, 0xF>(x, 0.0f));
    x = fmaxf(x, dpp_f<0x114, 0xF>(x, 0.0f));
    x = fmaxf(x, dpp_f<0x118, 0xF>(x, 0.0f));
    x = fmaxf(x, dpp_f<0x142, 0xA>(x, 0.0f));
    x = fmaxf(x, dpp_f<0x143, 0xC>(x, 0.0f));
    return x;
}
__device__ __forceinline__ float excl_shift1(float x, float ident) {
    return dpp_f<0x138, 0xF>(x, ident);  // wave_shr1
}
__device__ __forceinline__ float bcast63(float x) {
    return __int_as_float(__builtin_amdgcn_readlane(__float_as_int(x), 63));
}
__device__ __forceinline__ float wave_total(float x) {
    return bcast63(scan_incl_add(x));
}

__global__ __launch_bounds__(WPB * 64)
void volrender_kernel(const float* __restrict__ ro_g,
                      const float* __restrict__ rd_g,
                      const float* __restrict__ Wd_g,
                      const float* __restrict__ Wc_g,
                      float* __restrict__ out, int N) {
    __shared__ float  s_cdf[WPB][64];   // inclusive cdf
    __shared__ float  s_ts[WPB][64];    // importance t_samples (sorted by construction)
    __shared__ float  s_m[WPB][128];    // merged fine t values
    __shared__ float2 s_fa[WPB][128];   // (sigma, c0)
    __shared__ float2 s_fb[WPB][128];   // (c1, c2)

    const int lane = threadIdx.x & 63;
    const int wid  = threadIdx.x >> 6;
    int ray = blockIdx.x * WPB + wid;
    if (ray >= N) ray = N - 1;

    const float ox = ro_g[ray * 3 + 0], oy = ro_g[ray * 3 + 1], oz = ro_g[ray * 3 + 2];
    const float dx = rd_g[ray * 3 + 0], dy = rd_g[ray * 3 + 1], dz = rd_g[ray * 3 + 2];
    const float wd0 = Wd_g[0], wd1 = Wd_g[1], wd2 = Wd_g[2];
    float wc[9];
#pragma unroll
    for (int i = 0; i < 9; ++i) wc[i] = Wc_g[i];

    // field is linear in t along the ray: dd(t)=dd0+t*dd1, x_k(t)=e_k+t*f_k
    const float dd0 = ox * wd0 + oy * wd1 + oz * wd2;
    const float dd1 = dx * wd0 + dy * wd1 + dz * wd2;
    const float e0 = ox * wc[0] + oy * wc[3] + oz * wc[6];
    const float f0 = dx * wc[0] + dy * wc[3] + dz * wc[6];
    const float e1 = ox * wc[1] + oy * wc[4] + oz * wc[7];
    const float f1 = dx * wc[1] + dy * wc[4] + dz * wc[7];
    const float e2 = ox * wc[2] + oy * wc[5] + oz * wc[8];
    const float f2 = dx * wc[2] + dy * wc[5] + dz * wc[8];

    const long Nl = N;
    float* out_rgb  = out;
    float* out_dep  = out + 3 * Nl;
    float* out_acc  = out + 4 * Nl;
    float* out_frgb = out + 5 * Nl;
    float* out_fdep = out + 8 * Nl;
    float* out_facc = out + 9 * Nl;

    // ---------------- coarse pass: lane = sample ----------------
    const float t_c = tval(lane);
    const float sig_c = softplus_f(dd0 + t_c * dd1);
    const float c0_c  = sigmoid_f(e0 + t_c * f0);
    const float c1_c  = sigmoid_f(e1 + t_c * f1);
    const float c2_c  = sigmoid_f(e2 + t_c * f2);

    const float dist_c  = (lane < 63) ? (tval(lane + 1) - t_c) : FAR_DIST;
    const float alpha_c = 1.0f - __expf(-sig_c * dist_c);
    const float incl_c  = scan_incl_mul(1.0f - alpha_c + EPS_T_C);
    const float trans_c = excl_shift1(incl_c, 1.0f);
    const float w = alpha_c * trans_c;

    // single scan gives cdf, total, and acc (= total - 64*eps, err ~1e-7)
    const float S     = scan_incl_add(w + EPS_W_C);
    const float total = bcast63(S);
    const float cdf   = S * rcp_fast(total);
    const float accw  = total - 64.0f * EPS_W_C;
    const float dep   = wave_total(w * t_c);
    const float r0    = wave_total(w * c0_c);
    const float r1    = wave_total(w * c1_c);
    const float r2    = wave_total(w * c2_c);
    if (lane == 0) {
        const float bg = 1.0f - accw;
        out_rgb[ray * 3 + 0] = r0 + bg;
        out_rgb[ray * 3 + 1] = r1 + bg;
        out_rgb[ray * 3 + 2] = r2 + bg;
        out_dep[ray] = dep;
        out_acc[ray] = accw;
    }
    s_cdf[wid][lane] = cdf;
    __syncthreads();

    // ------------- inverse-CDF sampling: per-lane binary search -------------
    // Exact emulation of np.searchsorted(cdf65, u, 'right'): identical
    // comparisons/traversal even if cdf has ulp-level non-monotonicity.
    float bv;
    {
        const float u = (float)lane * (1.0f / 63.0f);
        int lo = 0, hi = 64;
        while (lo < hi) {
            int mid = (lo + hi) >> 1;
            if (s_cdf[wid][mid] <= u) lo = mid + 1; else hi = mid;
        }
        const int below = lo;                 // clip(idx-1,0,64), idx = lo+1
        const int above = min(lo + 1, 64);
        const float cdf0s = __shfl(cdf, max(below - 1, 0));
        const float cdf0  = (below == 0) ? 0.0f : cdf0s;
        const float cdf1  = __shfl(cdf, above - 1);
        const float bin0  = tval(min(below, 63));
        const float bin1  = tval(min(above, 63));
        float denom = cdf1 - cdf0;
        if (denom < EPS_W_C) denom = 1.0f;
        const float tt = (u - cdf0) * rcp_fast(denom);
        bv = bin0 + tt * (bin1 - bin0);
        // Enforce sortedness by construction (<=1 ulp perturbation in the
        // normal case): makes the merge-rank pair provably a permutation.
        bv = scan_max_f(bv);
        s_ts[wid][lane] = bv;
    }
    __syncthreads();

    // ------------- merge via two per-lane binary searches -------------
    {
        // rank of analytic A[lane]: lane + #{B_j < A[lane]}  (s_ts sorted)
        const float av = t_c;
        int lo = 0, hi = 64;
        while (lo < hi) {
            int mid = (lo + hi) >> 1;
            if (s_ts[wid][mid] < av) lo = mid + 1; else hi = mid;
        }
        const int rankA = lane + lo;
        // rank of B[lane]: lane + #{A_i <= B[lane]}  (analytic, register-only)
        lo = 0; hi = 64;
        while (lo < hi) {
            int mid = (lo + hi) >> 1;
            if (tval(mid) <= bv) lo = mid + 1; else hi = mid;
        }
        const int rankB = lane + lo;

        // field eval at the importance sample (only fresh eval of the fine pass)
        const float sigb = softplus_f(dd0 + bv * dd1);
        const float b0   = sigmoid_f(e0 + bv * f0);
        const float b1   = sigmoid_f(e1 + bv * f1);
        const float b2   = sigmoid_f(e2 + bv * f2);

        s_m[wid][rankA]  = t_c;
        s_m[wid][rankB]  = bv;
        s_fa[wid][rankA] = make_float2(sig_c, c0_c);
        s_fa[wid][rankB] = make_float2(sigb, b0);
        s_fb[wid][rankA] = make_float2(c1_c, c2_c);
        s_fb[wid][rankB] = make_float2(b1, b2);
    }
    __syncthreads();

    // ---------------- fine composite: 128 samples, 2 per lane ----------------
    {
        float faccw = 0.0f, fdep = 0.0f, fr0 = 0.0f, fr1 = 0.0f, fr2 = 0.0f;
        float carry = 1.0f;
#pragma unroll
        for (int h = 0; h < 2; ++h) {
            const int e = h * 64 + lane;
            const float t  = s_m[wid][e];
            const float tn = s_m[wid][min(e + 1, 127)];
            const float dist = (e < 127) ? (tn - t) : FAR_DIST;

            const float2 fa = s_fa[wid][e];
            const float2 fb = s_fb[wid][e];
            const float alpha = 1.0f - __expf(-fa.x * dist);
            const float incl  = scan_incl_mul(1.0f - alpha + EPS_T_C);
            const float trans = carry * excl_shift1(incl, 1.0f);
            const float w2 = alpha * trans;

            faccw += w2;
            fdep  += w2 * t;
            fr0   += w2 * fa.y;
            fr1   += w2 * fb.x;
            fr2   += w2 * fb.y;
            carry *= bcast63(incl);
        }
        faccw = wave_total(faccw);
        fdep  = wave_total(fdep);
        fr0   = wave_total(fr0);
        fr1   = wave_total(fr1);
        fr2   = wave_total(fr2);
        if (lane == 0) {
            const float bg = 1.0f - faccw;
            out_frgb[ray * 3 + 0] = fr0 + bg;
            out_frgb[ray * 3 + 1] = fr1 + bg;
            out_frgb[ray * 3 + 2] = fr2 + bg;
            out_fdep[ray] = fdep;
            out_facc[ray] = faccw;
        }
    }
}

extern "C" void kernel_launch(void* const* d_in, const int* in_sizes, int n_in,
                              void* d_out, int out_size, void* d_ws, size_t ws_size,
                              hipStream_t stream) {
    const float* ro = (const float*)d_in[0];
    const float* rd = (const float*)d_in[1];
    // d_in[2] exposure_values, d_in[5] appearance_ids: unused by reference
    const float* Wd = (const float*)d_in[3];
    const float* Wc = (const float*)d_in[4];
    float* out = (float*)d_out;

    const int N = in_sizes[0] / 3;
    const int grid = (N + WPB - 1) / WPB;
    volrender_kernel<<<grid, WPB * 64, 0, stream>>>(ro, rd, Wd, Wc, out, N);
}

// Round 8
// 104.449 us; speedup vs baseline: 1.0216x; 1.0216x over previous
//
#include <hip/hip_runtime.h>
#include <math.h>

#define WPB 4  // waves (rays) per block -> 256 threads

#define NEAR_T   2.0f
#define FAR_T    6.0f
#define EPS_W_C  1e-5f
#define EPS_T_C  1e-10f
#define FAR_DIST 1e10f

__device__ __forceinline__ float tval(int i) {
    return NEAR_T + (FAR_T - NEAR_T) * ((float)i * (1.0f / 63.0f));
}
__device__ __forceinline__ float rcp_fast(float x) {
    return __builtin_amdgcn_rcpf(x);
}

__device__ __forceinline__ float softplus_f(float x) {
    // Two-path log1p: must preserve tiny values (sigma ~1e-13 still saturates
    // alpha at dist=1e10 — R2 failure was __logf(1+e) rounding 1+e -> 1).
    const float e = __expf(-fabsf(x));
    const float big   = __logf(1.0f + e);                          // e > 2^-7
    const float small = e * (1.0f - e * (0.5f - e * 0.33333334f)); // e <= 2^-7, rel err ~1e-7
    return fmaxf(x, 0.0f) + ((e > 0.0078125f) ? big : small);
}
__device__ __forceinline__ float sigmoid_f(float x) {
    return rcp_fast(1.0f + __expf(-x));
}

// ---- DPP cross-lane (VALU pipe) ----
template<int CTRL, int MASK>
__device__ __forceinline__ float dpp_f(float x, float old) {
    return __int_as_float(__builtin_amdgcn_update_dpp(
        __float_as_int(old), __float_as_int(x), CTRL, MASK, 0xF, false));
}

__device__ __forceinline__ float scan_incl_add(float x) {
    x += dpp_f<0x111, 0xF>(x, 0.0f);
    x += dpp_f<0x112, 0xF>(x, 0.0f);
    x += dpp_f<0x114, 0xF>(x, 0.0f);
    x += dpp_f<0x118, 0xF>(x, 0.0f);
    x += dpp_f<0x142, 0xA>(x, 0.0f);   // row_bcast15
    x += dpp_f<0x143, 0xC>(x, 0.0f);   // row_bcast31
    return x;
}
__device__ __forceinline__ float scan_incl_mul(float x) {
    x *= dpp_f<0x111, 0xF>(x, 1.0f);
    x *= dpp_f<0x112, 0xF>(x, 1.0f);
    x *= dpp_f<0x114, 0xF>(x, 1.0f);
    x *= dpp_f<0x118, 0xF>(x, 1.0f);
    x *= dpp_f<0x142, 0xA>(x, 1.0f);
    x *= dpp_f<0x143, 0xC>(x, 1.0f);
    return x;
}
__device__ __forceinline__ float scan_max_f(float x) { // inclusive max-scan, values >= 0
    x = fmaxf(x, dpp_f<0x111, 0xF>(x, 0.0f));
    x = fmaxf(x, dpp_f<0x112, 0xF>(x, 0.0f));
    x = fmaxf(x, dpp_f<0x114, 0xF>(x, 0.0f));
    x = fmaxf(x, dpp_f<0x118, 0xF>(x, 0.0f));
    x = fmaxf(x, dpp_f<0x142, 0xA>(x, 0.0f));
    x = fmaxf(x, dpp_f<0x143, 0xC>(x, 0.0f));
    return x;
}
__device__ __forceinline__ float excl_shift1(float x, float ident) {
    return dpp_f<0x138, 0xF>(x, ident);  // wave_shr1: lane i <- lane i-1
}
__device__ __forceinline__ float shift_left1(float x, float fill) {
    return dpp_f<0x130, 0xF>(x, fill);   // wave_shl1: lane i <- lane i+1; lane63 <- fill
}
__device__ __forceinline__ float bcast63(float x) {
    return __int_as_float(__builtin_amdgcn_readlane(__float_as_int(x), 63));
}
__device__ __forceinline__ float wave_total(float x) {
    return bcast63(scan_incl_add(x));
}

__global__ __launch_bounds__(WPB * 64)
void volrender_kernel(const float* __restrict__ ro_g,
                      const float* __restrict__ rd_g,
                      const float* __restrict__ Wd_g,
                      const float* __restrict__ Wc_g,
                      float* __restrict__ out, int N) {
    __shared__ float  s_m[WPB][128];    // merged fine t values
    __shared__ float4 s_f[WPB][128];    // (sigma, c0, c1, c2) per merged sample

    const int lane = threadIdx.x & 63;
    const int wid  = threadIdx.x >> 6;
    int ray = blockIdx.x * WPB + wid;
    if (ray >= N) ray = N - 1;  // dup work, same writes; keeps barrier uniform

    const float ox = ro_g[ray * 3 + 0], oy = ro_g[ray * 3 + 1], oz = ro_g[ray * 3 + 2];
    const float dx = rd_g[ray * 3 + 0], dy = rd_g[ray * 3 + 1], dz = rd_g[ray * 3 + 2];
    const float wd0 = Wd_g[0], wd1 = Wd_g[1], wd2 = Wd_g[2];
    float wc[9];
#pragma unroll
    for (int i = 0; i < 9; ++i) wc[i] = Wc_g[i];

    // field is linear in t along the ray: dd(t)=dd0+t*dd1, x_k(t)=e_k+t*f_k
    const float dd0 = ox * wd0 + oy * wd1 + oz * wd2;
    const float dd1 = dx * wd0 + dy * wd1 + dz * wd2;
    const float e0 = ox * wc[0] + oy * wc[3] + oz * wc[6];
    const float f0 = dx * wc[0] + dy * wc[3] + dz * wc[6];
    const float e1 = ox * wc[1] + oy * wc[4] + oz * wc[7];
    const float f1 = dx * wc[1] + dy * wc[4] + dz * wc[7];
    const float e2 = ox * wc[2] + oy * wc[5] + oz * wc[8];
    const float f2 = dx * wc[2] + dy * wc[5] + dz * wc[8];

    const long Nl = N;
    float* out_rgb  = out;
    float* out_dep  = out + 3 * Nl;
    float* out_acc  = out + 4 * Nl;
    float* out_frgb = out + 5 * Nl;
    float* out_fdep = out + 8 * Nl;
    float* out_facc = out + 9 * Nl;

    // ---------------- coarse pass: lane = sample ----------------
    const float t_c = tval(lane);
    const float sig_c = softplus_f(dd0 + t_c * dd1);
    const float c0_c  = sigmoid_f(e0 + t_c * f0);
    const float c1_c  = sigmoid_f(e1 + t_c * f1);
    const float c2_c  = sigmoid_f(e2 + t_c * f2);

    const float dist_c  = (lane < 63) ? (tval(lane + 1) - t_c) : FAR_DIST;
    const float alpha_c = 1.0f - __expf(-sig_c * dist_c);
    const float incl_c  = scan_incl_mul(1.0f - alpha_c + EPS_T_C);
    const float trans_c = excl_shift1(incl_c, 1.0f);
    const float w = alpha_c * trans_c;

    // single scan gives cdf, total, and acc (= total - 64*eps, err ~1e-7)
    const float S     = scan_incl_add(w + EPS_W_C);
    const float total = bcast63(S);
    const float cdf   = S * rcp_fast(total);
    const float accw  = total - 64.0f * EPS_W_C;
    const float dep   = wave_total(w * t_c);
    const float r0    = wave_total(w * c0_c);
    const float r1    = wave_total(w * c1_c);
    const float r2    = wave_total(w * c2_c);
    if (lane == 0) {
        const float bg = 1.0f - accw;
        out_rgb[ray * 3 + 0] = r0 + bg;
        out_rgb[ray * 3 + 1] = r1 + bg;
        out_rgb[ray * 3 + 2] = r2 + bg;
        out_dep[ray] = dep;
        out_acc[ray] = accw;
    }

    // ------------- inverse-CDF sampling: shfl-based bisect -------------
    // below = #{k: cdf_k <= u}, searched over the register-resident cdf via
    // __shfl. vlo tracks last accepted probe (= cdf[below-1], init 0 handles
    // below==0); vhi tracks last rejected in-range probe (= cdf[below]).
    float bv;
    {
        const float u = (float)lane * (1.0f / 63.0f);
        int below = 0;
        float vlo = 0.0f, vhi = 0.0f;
#pragma unroll
        for (int s = 64; s >= 1; s >>= 1) {
            const int cand = below + s;            // probe cdf[cand-1]
            const float v = __shfl(cdf, min(cand, 64) - 1);
            if (cand <= 64) {
                if (v <= u) { below = cand; vlo = v; }
                else        { vhi = v; }
            }
        }
        const int above = min(below + 1, 64);
        const float cdf0 = vlo;                       // 0 if below==0
        const float cdf1 = (below >= 64) ? vlo : vhi; // cdf[above-1]
        const float bin0 = tval(min(below, 63));
        const float bin1 = tval(min(above, 63));
        float denom = cdf1 - cdf0;
        if (denom < EPS_W_C) denom = 1.0f;
        const float tt = (u - cdf0) * rcp_fast(denom);
        bv = bin0 + tt * (bin1 - bin0);
        // sortedness by construction (<=1 ulp perturbation): merge ranks
        // below are then a provable bijection.
        bv = scan_max_f(bv);
    }

    // ------------- merge ranks -------------
    // rank of B[lane]: lane + m, m = #{i: tval(i) <= bv} — analytic guess +
    // exact-predicate fixups, register-only (per-lane, no cross-lane dep).
    int m = (int)((bv - NEAR_T) * 15.75f) + 1;
    m = min(max(m, 0), 64);
#pragma unroll
    for (int it = 0; it < 3; ++it) if (m > 0 && tval(m - 1) > bv) --m;
#pragma unroll
    for (int it = 0; it < 3; ++it) if (m < 64 && tval(m) <= bv) ++m;
    const int rankB = lane + m;

    // rank of A[lane]: lane + #{j: bv_j < t_c} — shfl bisect over sorted bv.
    int pos2 = 0;
#pragma unroll
    for (int s = 64; s >= 1; s >>= 1) {
        const int cand = pos2 + s;
        const float v = __shfl(bv, min(cand, 64) - 1);
        if (cand <= 64 && v < t_c) pos2 = cand;
    }
    const int rankA = lane + pos2;

    // field eval at the importance sample (only fresh eval of the fine pass)
    const float sigb = softplus_f(dd0 + bv * dd1);
    const float b0   = sigmoid_f(e0 + bv * f0);
    const float b1   = sigmoid_f(e1 + bv * f1);
    const float b2   = sigmoid_f(e2 + bv * f2);

    s_m[wid][rankA] = t_c;
    s_m[wid][rankB] = bv;
    s_f[wid][rankA] = make_float4(sig_c, c0_c, c1_c, c2_c);
    s_f[wid][rankB] = make_float4(sigb, b0, b1, b2);
    __syncthreads();

    // ---------------- fine composite: 128 samples, 2 per lane ----------------
    {
        const float t0 = s_m[wid][lane];
        const float t1 = s_m[wid][64 + lane];
        const float4 fv0 = s_f[wid][lane];
        const float4 fv1 = s_f[wid][64 + lane];

        // neighbor t via DPP wave_shl1 (lane i <- lane i+1); lane63 of the
        // low half takes t1's first element; e=127 uses FAR_DIST anyway.
        const float t1_first = __int_as_float(__builtin_amdgcn_readlane(__float_as_int(t1), 0));
        float tn0 = shift_left1(t0, 0.0f);
        tn0 = (lane == 63) ? t1_first : tn0;
        const float tn1 = shift_left1(t1, 0.0f);

        const float dist0 = tn0 - t0;
        const float dist1 = (lane == 63) ? FAR_DIST : (tn1 - t1);

        const float alpha0 = 1.0f - __expf(-fv0.x * dist0);
        const float alpha1 = 1.0f - __expf(-fv1.x * dist1);

        // two independent 64-wide scans; carry applied after (ILP)
        const float incl0 = scan_incl_mul(1.0f - alpha0 + EPS_T_C);
        const float incl1 = scan_incl_mul(1.0f - alpha1 + EPS_T_C);
        const float carry = bcast63(incl0);
        const float w0 = alpha0 * excl_shift1(incl0, 1.0f);
        const float w1 = alpha1 * (carry * excl_shift1(incl1, 1.0f));

        const float faccw = wave_total(w0 + w1);
        const float fdep  = wave_total(w0 * t0 + w1 * t1);
        const float fr0   = wave_total(w0 * fv0.y + w1 * fv1.y);
        const float fr1   = wave_total(w0 * fv0.z + w1 * fv1.z);
        const float fr2   = wave_total(w0 * fv0.w + w1 * fv1.w);
        if (lane == 0) {
            const float bg = 1.0f - faccw;
            out_frgb[ray * 3 + 0] = fr0 + bg;
            out_frgb[ray * 3 + 1] = fr1 + bg;
            out_frgb[ray * 3 + 2] = fr2 + bg;
            out_fdep[ray] = fdep;
            out_facc[ray] = faccw;
        }
    }
}

extern "C" void kernel_launch(void* const* d_in, const int* in_sizes, int n_in,
                              void* d_out, int out_size, void* d_ws, size_t ws_size,
                              hipStream_t stream) {
    const float* ro = (const float*)d_in[0];
    const float* rd = (const float*)d_in[1];
    // d_in[2] exposure_values, d_in[5] appearance_ids: unused by reference
    const float* Wd = (const float*)d_in[3];
    const float* Wc = (const float*)d_in[4];
    float* out = (float*)d_out;

    const int N = in_sizes[0] / 3;
    const int grid = (N + WPB - 1) / WPB;
    volrender_kernel<<<grid, WPB * 64, 0, stream>>>(ro, rd, Wd, Wc, out, N);
}

// Round 9
// 65.078 us; speedup vs baseline: 1.6397x; 1.6050x over previous
//
#include <hip/hip_runtime.h>
#include <math.h>

#define NEAR_T   2.0f
#define FAR_T    6.0f
#define EPS_W_C  1e-5f
#define EPS_T_C  1e-10f
#define FAR_DIST 1e10f

__device__ __forceinline__ float tval(int i) {
    return NEAR_T + (FAR_T - NEAR_T) * ((float)i * (1.0f / 63.0f));
}
__device__ __forceinline__ float rcp_fast(float x) {
    return __builtin_amdgcn_rcpf(x);
}
__device__ __forceinline__ float softplus_f(float x) {
    // Two-path log1p: must preserve tiny values (sigma ~1e-13 still saturates
    // alpha at dist=1e10 — R2 failure was __logf(1+e) rounding 1+e -> 1).
    const float e = __expf(-fabsf(x));
    const float big   = __logf(1.0f + e);                          // e > 2^-7
    const float small = e * (1.0f - e * (0.5f - e * 0.33333334f)); // e <= 2^-7, rel err ~1e-7
    return fmaxf(x, 0.0f) + ((e > 0.0078125f) ? big : small);
}
__device__ __forceinline__ float sigmoid_f(float x) {
    return rcp_fast(1.0f + __expf(-x));
}

// Thread-per-ray, fully fused streaming renderer.
//  pass1: coarse march (sequential cumprod == np order), coarse outputs + total.
//  pass2: two-pointer fused {inverse-CDF sampling + merge + fine composite}:
//         grid t's and importance t's are both increasing; samples of bin b lie
//         in [tval(b), tval(b+1)], so "grid b, then its samples" IS the sorted
//         merged order. cdf is regenerated incrementally at grid steps
//         (bit-identical formula to pass1). No LDS, no barriers, no shuffles.
__global__ __launch_bounds__(256)
void volrender_tpr(const float* __restrict__ ro_g,
                   const float* __restrict__ rd_g,
                   const float* __restrict__ Wd_g,
                   const float* __restrict__ Wc_g,
                   float* __restrict__ out, int N) {
    const int ray = blockIdx.x * 256 + threadIdx.x;
    if (ray >= N) return;

    const float ox = ro_g[ray * 3 + 0], oy = ro_g[ray * 3 + 1], oz = ro_g[ray * 3 + 2];
    const float dx = rd_g[ray * 3 + 0], dy = rd_g[ray * 3 + 1], dz = rd_g[ray * 3 + 2];
    const float wd0 = Wd_g[0], wd1 = Wd_g[1], wd2 = Wd_g[2];
    float wc[9];
#pragma unroll
    for (int k = 0; k < 9; ++k) wc[k] = Wc_g[k];

    // field is linear in t along the ray
    const float dd0 = ox * wd0 + oy * wd1 + oz * wd2;
    const float dd1 = dx * wd0 + dy * wd1 + dz * wd2;
    const float e0 = ox * wc[0] + oy * wc[3] + oz * wc[6];
    const float f0 = dx * wc[0] + dy * wc[3] + dz * wc[6];
    const float e1 = ox * wc[1] + oy * wc[4] + oz * wc[7];
    const float f1 = dx * wc[1] + dy * wc[4] + dz * wc[7];
    const float e2 = ox * wc[2] + oy * wc[5] + oz * wc[8];
    const float f2 = dx * wc[2] + dy * wc[5] + dz * wc[8];

    const long Nl = N;
    float* out_rgb  = out;
    float* out_dep  = out + 3 * Nl;
    float* out_acc  = out + 4 * Nl;
    float* out_frgb = out + 5 * Nl;
    float* out_fdep = out + 8 * Nl;
    float* out_facc = out + 9 * Nl;

    // ---------------- pass 1: coarse march ----------------
    float trans = 1.0f, acc = 0.0f, dep = 0.0f, r0 = 0.0f, r1 = 0.0f, r2 = 0.0f;
    float total = 0.0f;
#pragma unroll 4
    for (int i = 0; i < 64; ++i) {
        const float t = tval(i);
        const float sig = softplus_f(dd0 + t * dd1);
        const float c0 = sigmoid_f(e0 + t * f0);
        const float c1 = sigmoid_f(e1 + t * f1);
        const float c2 = sigmoid_f(e2 + t * f2);
        const float dist = (i < 63) ? (tval(i + 1) - t) : FAR_DIST;
        const float a = 1.0f - __expf(-sig * dist);
        const float w = a * trans;
        trans *= (1.0f - a + EPS_T_C);
        acc += w; dep += w * t;
        r0 += w * c0; r1 += w * c1; r2 += w * c2;
        total += w + EPS_W_C;
    }
    {
        const float bg = 1.0f - acc;
        out_rgb[ray * 3 + 0] = r0 + bg;
        out_rgb[ray * 3 + 1] = r1 + bg;
        out_rgb[ray * 3 + 2] = r2 + bg;
        out_dep[ray] = dep;
        out_acc[ray] = acc;
    }
    const float inv_total = rcp_fast(total);

    // ---------------- pass 2: fused sample + merge + fine ----------------
    float transc = 1.0f;                       // coarse trans (cdf regen)
    float transf = 1.0f;                       // fine trans
    float facc = 0.0f, fdep = 0.0f, fr0 = 0.0f, fr1 = 0.0f, fr2 = 0.0f;
    float lo, hi, bin0, bin1;                  // cdf bin state (lo=cdf[b-1], hi=cdf[b])
    int i, j = 0;                              // next grid idx / next u idx
    float pt, ps, p0, p1, p2;                  // previous merged element (lagged)

    // peel e=0: always grid 0 (u_0=0 < cdf_0 lands in bin 0, after grid 0)
    {
        const float t = tval(0);
        ps = softplus_f(dd0 + t * dd1);
        p0 = sigmoid_f(e0 + t * f0);
        p1 = sigmoid_f(e1 + t * f1);
        p2 = sigmoid_f(e2 + t * f2);
        const float distc = tval(1) - t;
        const float ac = 1.0f - __expf(-ps * distc);
        const float wcc = ac * transc;
        transc *= (1.0f - ac + EPS_T_C);
        lo = 0.0f;
        hi = (wcc + EPS_W_C) * inv_total;      // cdf[0]
        bin0 = t; bin1 = tval(1);
        i = 1;
        pt = t;
    }

#pragma unroll 2
    for (int e = 1; e < 128; ++e) {
        // importance-sample candidate from head u
        const float u = (float)j * (1.0f / 63.0f);
        float denom = hi - lo;
        denom = (denom < EPS_W_C) ? 1.0f : denom;
        const float ts = bin0 + (u - lo) * rcp_fast(denom) * (bin1 - bin0);
        // next merged element: sample iff head-u falls in current bin
        const bool samp = (j < 64) && ((i >= 64) || (u < hi));
        const float tg = tval(min(i, 63));
        const float t = samp ? ts : tg;

        // shared field eval at t
        const float sig = softplus_f(dd0 + t * dd1);
        const float c0 = sigmoid_f(e0 + t * f0);
        const float c1 = sigmoid_f(e1 + t * f1);
        const float c2 = sigmoid_f(e2 + t * f2);

        // fine composite of PREVIOUS element with dist = t - pt
        const float af = 1.0f - __expf(-ps * (t - pt));
        const float wf = af * transf;
        transf *= (1.0f - af + EPS_T_C);
        facc += wf; fdep += wf * pt;
        fr0 += wf * p0; fr1 += wf * p1; fr2 += wf * p2;

        // coarse/cdf advance (computed always, committed only on grid emit)
        const float distc = (i < 63) ? (tval(i + 1) - tg) : FAR_DIST;
        const float ac = 1.0f - __expf(-sig * distc);
        const float wcc = ac * transc;
        const float transc_n = transc * (1.0f - ac + EPS_T_C);
        const float hi_n = hi + (wcc + EPS_W_C) * inv_total;
        if (samp) {
            ++j;
        } else {
            transc = transc_n;
            lo = hi; hi = hi_n;
            bin0 = tg; bin1 = tval(min(i + 1, 63));
            ++i;
        }
        pt = t; ps = sig; p0 = c0; p1 = c1; p2 = c2;
    }

    // epilogue: last merged element gets FAR_DIST
    {
        const float af = 1.0f - __expf(-ps * FAR_DIST);
        const float wf = af * transf;
        facc += wf; fdep += wf * pt;
        fr0 += wf * p0; fr1 += wf * p1; fr2 += wf * p2;

        const float bg = 1.0f - facc;
        out_frgb[ray * 3 + 0] = fr0 + bg;
        out_frgb[ray * 3 + 1] = fr1 + bg;
        out_frgb[ray * 3 + 2] = fr2 + bg;
        out_fdep[ray] = fdep;
        out_facc[ray] = facc;
    }
}

extern "C" void kernel_launch(void* const* d_in, const int* in_sizes, int n_in,
                              void* d_out, int out_size, void* d_ws, size_t ws_size,
                              hipStream_t stream) {
    const float* ro = (const float*)d_in[0];
    const float* rd = (const float*)d_in[1];
    // d_in[2] exposure_values, d_in[5] appearance_ids: unused by reference
    const float* Wd = (const float*)d_in[3];
    const float* Wc = (const float*)d_in[4];
    float* out = (float*)d_out;

    const int N = in_sizes[0] / 3;
    const int grid = (N + 255) / 256;
    volrender_tpr<<<grid, 256, 0, stream>>>(ro, rd, Wd, Wc, out, N);
}

// Round 10
// 53.041 us; speedup vs baseline: 2.0117x; 1.2269x over previous
//
#include <hip/hip_runtime.h>
#include <math.h>

#define NEAR_T   2.0f
#define FAR_T    6.0f
#define EPS_W_C  1e-5f
#define EPS_T_C  1e-10f
#define FAR_DIST 1e10f
#define L2E      1.4426950408889634f

__device__ __forceinline__ float tval(int i) {
    return NEAR_T + (FAR_T - NEAR_T) * ((float)i * (1.0f / 63.0f));
}
__device__ __forceinline__ float rcp_fast(float x) { return __builtin_amdgcn_rcpf(x); }
__device__ __forceinline__ float exp2_f(float x)  { return __builtin_amdgcn_exp2f(x); }
__device__ __forceinline__ float log2_f(float x)  { return __builtin_amdgcn_logf(x); }

// base-2 softplus: input dd' = dd*log2e, returns sigma' = softplus(dd)*log2e.
// Two-path log2(1+e): must preserve tiny values (sigma ~1e-13 still saturates
// alpha at dist=1e10 — R2 failure). v_exp/v_log are native exp2/log2; |.| and
// negate fold into input modifiers.
__device__ __forceinline__ float softplus2_f(float xp) {
    const float e = exp2_f(-fabsf(xp));              // = exp(-|dd|)
    const float big   = log2_f(1.0f + e);            // e > 2^-7
    const float small = e * (1.4426950f - e * (0.72134751f - e * 0.48089835f)); // rel err ~1e-7
    return fmaxf(xp, 0.0f) + ((e > 0.0078125f) ? big : small);
}
__device__ __forceinline__ float sigmoid2_f(float xp) {  // xp = x*log2e
    return rcp_fast(1.0f + exp2_f(-xp));
}

// Thread-per-ray, fully fused streaming renderer (R9 structure) +
//  (a) pass1 stores unnormalized cdf prefix S_i in LDS; pass2's coarse/cdf
//      re-advance chain becomes one prefetched ds_read per bin entry.
//  (b) whole pipeline in base-2: per-ray coefficients pre-scaled by log2e.
__global__ __launch_bounds__(256)
void volrender_tpr(const float* __restrict__ ro_g,
                   const float* __restrict__ rd_g,
                   const float* __restrict__ Wd_g,
                   const float* __restrict__ Wc_g,
                   float* __restrict__ out, int N) {
    __shared__ float s_cdf[64][256];   // [i][tid]: 2 lanes/bank (free); gather
                                       // banks = tid%32 regardless of i (i*256%32==0)
    const int tid = threadIdx.x;
    const int ray = blockIdx.x * 256 + tid;
    if (ray >= N) return;

    const float ox = ro_g[ray * 3 + 0], oy = ro_g[ray * 3 + 1], oz = ro_g[ray * 3 + 2];
    const float dx = rd_g[ray * 3 + 0], dy = rd_g[ray * 3 + 1], dz = rd_g[ray * 3 + 2];
    const float wd0 = Wd_g[0], wd1 = Wd_g[1], wd2 = Wd_g[2];
    float wc[9];
#pragma unroll
    for (int k = 0; k < 9; ++k) wc[k] = Wc_g[k];

    // field is linear in t; scale all coefficients by log2e once
    const float dd0 = (ox * wd0 + oy * wd1 + oz * wd2) * L2E;
    const float dd1 = (dx * wd0 + dy * wd1 + dz * wd2) * L2E;
    const float e0 = (ox * wc[0] + oy * wc[3] + oz * wc[6]) * L2E;
    const float f0 = (dx * wc[0] + dy * wc[3] + dz * wc[6]) * L2E;
    const float e1 = (ox * wc[1] + oy * wc[4] + oz * wc[7]) * L2E;
    const float f1 = (dx * wc[1] + dy * wc[4] + dz * wc[7]) * L2E;
    const float e2 = (ox * wc[2] + oy * wc[5] + oz * wc[8]) * L2E;
    const float f2 = (dx * wc[2] + dy * wc[5] + dz * wc[8]) * L2E;

    const long Nl = N;
    float* out_rgb  = out;
    float* out_dep  = out + 3 * Nl;
    float* out_acc  = out + 4 * Nl;
    float* out_frgb = out + 5 * Nl;
    float* out_fdep = out + 8 * Nl;
    float* out_facc = out + 9 * Nl;

    // ---------------- pass 1: coarse march + cdf store ----------------
    float trans = 1.0f, acc = 0.0f, dep = 0.0f, r0 = 0.0f, r1 = 0.0f, r2 = 0.0f;
    float total = 0.0f;
#pragma unroll 4
    for (int i = 0; i < 64; ++i) {
        const float t = tval(i);
        const float sigp = softplus2_f(dd0 + t * dd1);
        const float c0 = sigmoid2_f(e0 + t * f0);
        const float c1 = sigmoid2_f(e1 + t * f1);
        const float c2 = sigmoid2_f(e2 + t * f2);
        const float dist = (i < 63) ? (tval(i + 1) - t) : FAR_DIST;
        const float a = 1.0f - exp2_f(-sigp * dist);
        const float w = a * trans;
        trans *= (1.0f - a + EPS_T_C);
        acc += w; dep += w * t;
        r0 += w * c0; r1 += w * c1; r2 += w * c2;
        total += w + EPS_W_C;
        s_cdf[i][tid] = total;                 // unnormalized inclusive prefix
    }
    {
        const float bg = 1.0f - acc;
        out_rgb[ray * 3 + 0] = r0 + bg;
        out_rgb[ray * 3 + 1] = r1 + bg;
        out_rgb[ray * 3 + 2] = r2 + bg;
        out_dep[ray] = dep;
        out_acc[ray] = acc;
    }
    const float inv_total = rcp_fast(total);

    // ---------------- pass 2: fused sample + merge + fine ----------------
    float transf = 1.0f;
    float facc = 0.0f, fdep = 0.0f, fr0 = 0.0f, fr1 = 0.0f, fr2 = 0.0f;
    float lo, hi, bin0, bin1;                  // cdf bin state
    int i, j = 0;                              // next grid idx / next u idx
    float pt, ps, p0, p1, p2;                  // previous merged element (lagged)
    float Snext;                               // prefetched S_i for next bin entry

    // peel e=0: always grid 0
    {
        const float t = tval(0);
        ps = softplus2_f(dd0 + t * dd1);
        p0 = sigmoid2_f(e0 + t * f0);
        p1 = sigmoid2_f(e1 + t * f1);
        p2 = sigmoid2_f(e2 + t * f2);
        lo = 0.0f;
        hi = s_cdf[0][tid] * inv_total;        // cdf[0]
        bin0 = t; bin1 = tval(1);
        i = 1;
        pt = t;
        Snext = s_cdf[1][tid];                 // prefetch S_1
    }

#pragma unroll 2
    for (int e = 1; e < 128; ++e) {
        // importance-sample candidate from head u (garbage if j>=64: unused)
        const float u = (float)j * (1.0f / 63.0f);
        float denom = hi - lo;
        denom = (denom < EPS_W_C) ? 1.0f : denom;
        const float ts = bin0 + (u - lo) * rcp_fast(denom) * (bin1 - bin0);
        // next merged element: sample iff head-u falls in current bin
        const bool samp = (j < 64) && ((i >= 64) || (u < hi));
        const float t = samp ? ts : bin1;      // tg == bin1 by construction

        // shared field eval at t (base-2)
        const float sig = softplus2_f(dd0 + t * dd1);
        const float c0 = sigmoid2_f(e0 + t * f0);
        const float c1 = sigmoid2_f(e1 + t * f1);
        const float c2 = sigmoid2_f(e2 + t * f2);

        // fine composite of PREVIOUS element with dist = t - pt
        const float af = 1.0f - exp2_f(-ps * (t - pt));
        const float wf = af * transf;
        transf *= (1.0f - af + EPS_T_C);
        facc += wf; fdep += wf * pt;
        fr0 += wf * p0; fr1 += wf * p1; fr2 += wf * p2;

        if (samp) {
            ++j;
        } else {
            lo = hi;
            hi = Snext * inv_total;            // cdf[i], prefetched
            bin0 = bin1;
            bin1 = tval(min(i + 1, 63));
            ++i;
            Snext = s_cdf[min(i, 63)][tid];    // prefetch next bin's cdf
        }
        pt = t; ps = sig; p0 = c0; p1 = c1; p2 = c2;
    }

    // epilogue: last merged element gets FAR_DIST
    {
        const float af = 1.0f - exp2_f(-ps * FAR_DIST);
        const float wf = af * transf;
        facc += wf; fdep += wf * pt;
        fr0 += wf * p0; fr1 += wf * p1; fr2 += wf * p2;

        const float bg = 1.0f - facc;
        out_frgb[ray * 3 + 0] = fr0 + bg;
        out_frgb[ray * 3 + 1] = fr1 + bg;
        out_frgb[ray * 3 + 2] = fr2 + bg;
        out_fdep[ray] = fdep;
        out_facc[ray] = facc;
    }
}

extern "C" void kernel_launch(void* const* d_in, const int* in_sizes, int n_in,
                              void* d_out, int out_size, void* d_ws, size_t ws_size,
                              hipStream_t stream) {
    const float* ro = (const float*)d_in[0];
    const float* rd = (const float*)d_in[1];
    // d_in[2] exposure_values, d_in[5] appearance_ids: unused by reference
    const float* Wd = (const float*)d_in[3];
    const float* Wc = (const float*)d_in[4];
    float* out = (float*)d_out;

    const int N = in_sizes[0] / 3;
    const int grid = (N + 255) / 256;
    volrender_tpr<<<grid, 256, 0, stream>>>(ro, rd, Wd, Wc, out, N);
}

// Round 11
// 46.649 us; speedup vs baseline: 2.2874x; 1.1370x over previous
//
#include <hip/hip_runtime.h>
#include <math.h>

#define NEAR_T   2.0f
#define FAR_T    6.0f
#define EPS_W_C  1e-5f
#define EPS_T_C  1e-10f
#define FAR_DIST 1e10f
#define L2E      1.4426950408889634f
#define INV63    (1.0f / 63.0f)

typedef float v2f __attribute__((ext_vector_type(2)));

__device__ __forceinline__ float tval(int i) {
    return NEAR_T + (FAR_T - NEAR_T) * ((float)i * INV63);
}
__device__ __forceinline__ float rcp_fast(float x) { return __builtin_amdgcn_rcpf(x); }
__device__ __forceinline__ float exp2_f(float x)  { return __builtin_amdgcn_exp2f(x); }
__device__ __forceinline__ float log2_f(float x)  { return __builtin_amdgcn_logf(x); }
__device__ __forceinline__ v2f fma2(v2f a, v2f b, v2f c) {
    return __builtin_elementwise_fma(a, b, c);
}

// safe base-2 softplus (two-path log2(1+e)): preserves sigma down to ~1e-13,
// REQUIRED where dist=1e10 can saturate alpha from a tiny sigma (R2 failure).
__device__ __forceinline__ float softplus2_safe(float xp) {
    const float e = exp2_f(-fabsf(xp));
    const float big   = log2_f(1.0f + e);
    const float small = e * (1.4426950f - e * (0.72134751f - e * 0.48089835f));
    return fmaxf(xp, 0.0f) + ((e > 0.0078125f) ? big : small);
}

struct FieldV { float sig; float c2; v2f c01; };

// fast field eval: softplus without the small path (flushes sigma < 2^-24 to 0;
// alpha error < 2^-24*4 for bounded dists — only the FAR_DIST consumers need
// the safe version). Pairable math packed for v_pk_fma/v_pk_add.
__device__ __forceinline__ FieldV eval_fast(float t, v2f A0, v2f A1, v2f B0, v2f B1) {
    const v2f tt = {t, t};
    const v2f a = fma2(tt, A1, A0);          // (dd', c2-arg)
    const v2f b = fma2(tt, B1, B0);          // (c0-arg, c1-arg)
    const float ea  = exp2_f(-fabsf(a.x));
    const float ec  = exp2_f(-a.y);
    const float eb0 = exp2_f(-b.x);
    const float eb1 = exp2_f(-b.y);
    const v2f pa = (v2f){ea, ec} + (v2f){1.0f, 1.0f};
    const v2f pb = (v2f){eb0, eb1} + (v2f){1.0f, 1.0f};
    FieldV r;
    r.sig = fmaxf(a.x, 0.0f) + log2_f(pa.x);
    r.c2  = rcp_fast(pa.y);
    r.c01 = (v2f){rcp_fast(pb.x), rcp_fast(pb.y)};
    return r;
}

__global__ __launch_bounds__(256)
void volrender_tpr(const float* __restrict__ ro_g,
                   const float* __restrict__ rd_g,
                   const float* __restrict__ Wd_g,
                   const float* __restrict__ Wc_g,
                   float* __restrict__ out, int N) {
    __shared__ float s_cdf[64][256];   // [i][tid]: banks = tid%32, conflict-free

    const int tid = threadIdx.x;
    const int ray = blockIdx.x * 256 + tid;
    if (ray >= N) return;

    const float ox = ro_g[ray * 3 + 0], oy = ro_g[ray * 3 + 1], oz = ro_g[ray * 3 + 2];
    const float dx = rd_g[ray * 3 + 0], dy = rd_g[ray * 3 + 1], dz = rd_g[ray * 3 + 2];
    const float wd0 = Wd_g[0], wd1 = Wd_g[1], wd2 = Wd_g[2];
    float wcm[9];
#pragma unroll
    for (int k = 0; k < 9; ++k) wcm[k] = Wc_g[k];

    // affine-in-t field coefficients, pre-scaled by log2e; packed as
    // A = (density, color2), B = (color0, color1)
    const v2f A0 = { (ox * wd0 + oy * wd1 + oz * wd2) * L2E,
                     (ox * wcm[2] + oy * wcm[5] + oz * wcm[8]) * L2E };
    const v2f A1 = { (dx * wd0 + dy * wd1 + dz * wd2) * L2E,
                     (dx * wcm[2] + dy * wcm[5] + dz * wcm[8]) * L2E };
    const v2f B0 = { (ox * wcm[0] + oy * wcm[3] + oz * wcm[6]) * L2E,
                     (ox * wcm[1] + oy * wcm[4] + oz * wcm[7]) * L2E };
    const v2f B1 = { (dx * wcm[0] + dy * wcm[3] + dz * wcm[6]) * L2E,
                     (dx * wcm[1] + dy * wcm[4] + dz * wcm[7]) * L2E };

    const float W = (FAR_T - NEAR_T) * INV63;   // bin width (constant; ulp-level
                                                // vs per-bin exact diffs — harmless)
    const float TMAX = tval(63);

    const long Nl = N;
    float* out_rgb  = out;
    float* out_dep  = out + 3 * Nl;
    float* out_acc  = out + 4 * Nl;
    float* out_frgb = out + 5 * Nl;
    float* out_fdep = out + 8 * Nl;
    float* out_facc = out + 9 * Nl;

    // ---------------- pass 1: coarse march + cdf store ----------------
    float trans = 1.0f, acc = 0.0f, dep = 0.0f, r2 = 0.0f, total = 0.0f;
    v2f r01 = {0.0f, 0.0f};
    float t = NEAR_T;
#pragma unroll 4
    for (int i = 0; i < 63; ++i) {
        const FieldV F = eval_fast(t, A0, A1, B0, B1);
        const float a = 1.0f - exp2_f(-F.sig * W);
        const float w = a * trans;
        trans *= (1.0f - a + EPS_T_C);
        acc += w; dep = fmaf(w, t, dep);
        r01 = fma2((v2f){w, w}, F.c01, r01);
        r2 = fmaf(w, F.c2, r2);
        total += w + EPS_W_C;
        s_cdf[i][tid] = total;
        t += W;
    }
    {   // i = 63: dist = FAR_DIST -> needs safe softplus
        FieldV F = eval_fast(t, A0, A1, B0, B1);
        const float sig = softplus2_safe(fmaf(t, A1.x, A0.x));
        const float a = 1.0f - exp2_f(-sig * FAR_DIST);
        const float w = a * trans;
        acc += w; dep = fmaf(w, t, dep);
        r01 = fma2((v2f){w, w}, F.c01, r01);
        r2 = fmaf(w, F.c2, r2);
        total += w + EPS_W_C;
        s_cdf[63][tid] = total;
    }
    {
        const float bg = 1.0f - acc;
        out_rgb[ray * 3 + 0] = r01.x + bg;
        out_rgb[ray * 3 + 1] = r01.y + bg;
        out_rgb[ray * 3 + 2] = r2 + bg;
        out_dep[ray] = dep;
        out_acc[ray] = acc;
    }
    const float inv_total = rcp_fast(total);

    // ---------------- pass 2: fused sample + merge + fine ----------------
    float transf = 1.0f, facc = 0.0f, fdep = 0.0f, fr2 = 0.0f;
    v2f fr01 = {0.0f, 0.0f};
    float lo, hi, bin0, bin1, binw;
    int i, j = 0;
    float u = 0.0f;                         // = j/63, incremental (drift <= ~60 ulp)
    float pt, ps, pc2;                      // lagged previous merged element
    v2f pc01;
    float Snext;

    {   // peel e=0: always grid 0
        const float t0 = NEAR_T;
        const FieldV F = eval_fast(t0, A0, A1, B0, B1);
        ps = F.sig; pc01 = F.c01; pc2 = F.c2; pt = t0;
        lo = 0.0f;
        hi = s_cdf[0][tid] * inv_total;
        bin0 = NEAR_T; bin1 = NEAR_T + W; binw = bin1 - bin0;
        i = 1;
        Snext = s_cdf[1][tid];
    }

#pragma unroll 4
    for (int e = 1; e < 128; ++e) {
        // importance-sample candidate from head u
        float dnm = hi - lo;
        dnm = (dnm < EPS_W_C) ? 1.0f : dnm;
        const float ts = fmaf((u - lo) * rcp_fast(dnm), binw, bin0);
        const bool samp = (j < 64) && ((i >= 64) || (u < hi));
        const float tm = samp ? ts : bin1;

        const FieldV F = eval_fast(tm, A0, A1, B0, B1);

        // fine composite of PREVIOUS element with dist = tm - pt
        const float af = 1.0f - exp2_f(-ps * (tm - pt));
        const float wf = af * transf;
        transf *= (1.0f - af + EPS_T_C);
        facc += wf; fdep = fmaf(wf, pt, fdep);
        fr01 = fma2((v2f){wf, wf}, pc01, fr01);
        fr2 = fmaf(wf, pc2, fr2);

        if (samp) {
            ++j; u += INV63;
        } else {
            lo = hi;
            hi = Snext * inv_total;
            bin0 = bin1;
            bin1 = fminf(bin1 + W, TMAX);
            binw = bin1 - bin0;
            ++i;
            Snext = s_cdf[min(i, 63)][tid];
        }
        pt = tm; ps = F.sig; pc01 = F.c01; pc2 = F.c2;
    }

    {   // epilogue: last merged element gets FAR_DIST -> safe sigma recompute
        const float sig = softplus2_safe(fmaf(pt, A1.x, A0.x));
        const float af = 1.0f - exp2_f(-sig * FAR_DIST);
        const float wf = af * transf;
        facc += wf; fdep = fmaf(wf, pt, fdep);
        fr01 = fma2((v2f){wf, wf}, pc01, fr01);
        fr2 = fmaf(wf, pc2, fr2);

        const float bg = 1.0f - facc;
        out_frgb[ray * 3 + 0] = fr01.x + bg;
        out_frgb[ray * 3 + 1] = fr01.y + bg;
        out_frgb[ray * 3 + 2] = fr2 + bg;
        out_fdep[ray] = fdep;
        out_facc[ray] = facc;
    }
}

extern "C" void kernel_launch(void* const* d_in, const int* in_sizes, int n_in,
                              void* d_out, int out_size, void* d_ws, size_t ws_size,
                              hipStream_t stream) {
    const float* ro = (const float*)d_in[0];
    const float* rd = (const float*)d_in[1];
    // d_in[2] exposure_values, d_in[5] appearance_ids: unused by reference
    const float* Wd = (const float*)d_in[3];
    const float* Wc = (const float*)d_in[4];
    float* out = (float*)d_out;

    const int N = in_sizes[0] / 3;
    const int grid = (N + 255) / 256;
    volrender_tpr<<<grid, 256, 0, stream>>>(ro, rd, Wd, Wc, out, N);
}